// Round 7
// baseline (242.772 us; speedup 1.0000x reference)
//
#include <hip/hip_runtime.h>

// Yoshida 4th-order integrator, Gamma(v) = W @ (U v)^2, B=4096, D=1024, R=256.
// R13 (resubmit; round 6 was an infra failure, kernel never ran).
// De-stage the R12 R-space algorithm. R12 post-mortem: math/layout right
// (passed, conflicts 65K) but phase-serialized at 53us: every LDS stage
// (vA/fA 64K, M 128K) = a memory burst + barrier with idle compute, and
// 152KB LDS pinned 1 block/CU. Fixes:
//  - v/f B-frags loaded DIRECTLY from global in phase 1 (lane l reads 32B of
//    row b0+(l&15); 4 lanes/row are consecutive 32B chunks -> fully coalesced)
//    and converted in-reg via __bf16 casts (compiler emits v_cvt_pk_bf16_f32).
//    No vA/fA LDS, no leading barrier: waves stream from kernel entry.
//  - M read as bf16 A-frags straight from global (128KB shared by all blocks
//    -> L2 broadcast), held in 32 VGPRs across BOTH phase-2 GEMMs.
//  - mm_kernel v2: atomic-free full-K dot products (64 blocks), writes M
//    directly as bf16 frags; no M f32 scratch, no zero-init pass.
//  - LDS = H2B + PB + QB only (24KB); barriers 6 -> 4.
// Kept from R12 (verified): R-space math h_{s+1}=h_s+dt*d_s*(g-M h2_s),
// P/Q suffix accumulation, all fragment layouts, phase-3 W global ring,
// fused f32 epilogue.

#define BSZ 4096
#define DD 1024
#define RR 256

// ws layout (1.125MB)
#define U_OFF 0u                  // 512KB bf16 U A-frags: (nt*32+p)*1024 + l*16
#define W_OFF (512u * 1024u)      // 512KB bf16 W A-frags: (dt*8+p)*1024 + l*16
#define M_OFF (1024u * 1024u)     // 128KB bf16 M A-frags: (nt*8+p)*1024 + l*16

typedef unsigned char uchar;
typedef unsigned int uint;
typedef unsigned short ushort;
typedef __attribute__((ext_vector_type(4))) float f32x4;
typedef __attribute__((ext_vector_type(4))) uint uint4v;
typedef __attribute__((ext_vector_type(8))) short short8;

__device__ inline uint f2bf1(float x) {
    uint u = __builtin_bit_cast(uint, x);
    return (u + 0x7FFFu + ((u >> 16) & 1u)) >> 16;     // RNE f32->bf16
}
__device__ inline uint f2bf2(float lo, float hi) {
    return f2bf1(lo) | (f2bf1(hi) << 16);
}
// HW conversion path: compiler lowers __bf16 casts to v_cvt_pk_bf16_f32
__device__ inline uint cvt2(float a, float b) {
    const __bf16 lo = (__bf16)a, hi = (__bf16)b;
    return (uint)__builtin_bit_cast(ushort, lo) |
           ((uint)__builtin_bit_cast(ushort, hi) << 16);
}
__device__ inline uint4v frag8(const float4 a, const float4 b) {
    uint4v o;
    o.x = cvt2(a.x, a.y); o.y = cvt2(a.z, a.w);
    o.z = cvt2(b.x, b.y); o.w = cvt2(b.z, b.w);
    return o;
}

// ---- pack U and W into bf16 fragment-major A-frags -------------------------
// Fragment: slice(tile,p) = 1KB; lane l holds row=(l&15), k=p*32+(l>>4)*8+j.
__global__ __launch_bounds__(256) void pack_kernel(
    const float* __restrict__ U, const float* __restrict__ W,
    uchar* __restrict__ ws)
{
    const int g = blockIdx.x * 256 + threadIdx.x;       // 0..49151
    const int l = g & 63;
    const float* src;
    size_t dst;
    if (g < 32768) {                 // U: 16 nt x 32 p slices
        const int slice = g >> 6, nt = slice >> 5, p = slice & 31;
        src = U + (size_t)(nt * 16 + (l & 15)) * DD + p * 32 + (l >> 4) * 8;
        dst = U_OFF + (size_t)slice * 1024 + l * 16;
    } else {                         // W: 64 dt x 8 p slices
        const int g2 = g - 32768;
        const int slice = g2 >> 6, dt_ = slice >> 3, p = slice & 7;
        src = W + (size_t)(dt_ * 16 + (l & 15)) * RR + p * 32 + (l >> 4) * 8;
        dst = W_OFF + (size_t)slice * 1024 + l * 16;
    }
    const float4 a0 = *reinterpret_cast<const float4*>(src);
    const float4 a1 = *reinterpret_cast<const float4*>(src + 4);
    uint4v o;
    o.x = f2bf2(a0.x, a0.y); o.y = f2bf2(a0.z, a0.w);
    o.z = f2bf2(a1.x, a1.y); o.w = f2bf2(a1.z, a1.w);
    *reinterpret_cast<uint4v*>(ws + dst) = o;
}

// ---- M = U @ W, atomic-free, bf16 frag output ------------------------------
// 64 blocks x 1024 thr: thread = one (r, c), full-K dot product.
// U[r][*] is wave-uniform (scalar path); W[*][c] coalesced 256B per k.
__global__ __launch_bounds__(1024) void mm_kernel(
    const float* __restrict__ U, const float* __restrict__ W,
    uchar* __restrict__ ws)
{
    const int rt = blockIdx.x >> 2;          // 16-row tile 0..15
    const int cc = blockIdx.x & 3;           // 64-col chunk 0..3
    const int r  = rt * 16 + (threadIdx.x >> 6);
    const int c  = cc * 64 + (threadIdx.x & 63);
    const float* ur = U + (size_t)r * DD;
    const float* wc = W + c;
    float acc = 0.f;
    #pragma unroll 2
    for (int k = 0; k < DD; k += 8) {
        const float4 u0 = *reinterpret_cast<const float4*>(ur + k);
        const float4 u1 = *reinterpret_cast<const float4*>(ur + k + 4);
        float wv[8];
        #pragma unroll
        for (int j = 0; j < 8; ++j) wv[j] = wc[(size_t)(k + j) * RR];
        acc += u0.x * wv[0] + u0.y * wv[1] + u0.z * wv[2] + u0.w * wv[3]
             + u1.x * wv[4] + u1.y * wv[5] + u1.z * wv[6] + u1.w * wv[7];
    }
    // frag address for element (row r, k=c): slice = (r>>4)*8 + (c>>5)
    const int slice = ((r >> 4) << 3) + (c >> 5);
    const int ll = (r & 15) | (((c >> 3) & 3) << 4);
    *reinterpret_cast<ushort*>(ws + M_OFF + (size_t)slice * 1024 + ll * 16 + (c & 7) * 2)
        = (ushort)f2bf1(acc);
}

// ---- fused integrator ------------------------------------------------------
__global__ __launch_bounds__(1024) void yoshida_fused_kernel(
    const float* __restrict__ x_in,
    const float* __restrict__ v_in,
    const float* __restrict__ force,
    const uchar* __restrict__ ws,
    float* __restrict__ x_out,
    float* __restrict__ v_out)
{
    __shared__ __align__(16) uchar H2B[8192];   // h2 B-frags, 8 slices
    __shared__ __align__(16) uchar PB[8192];    // P B-frags
    __shared__ __align__(16) uchar QB[8192];    // Q B-frags

    const int tid = threadIdx.x;
    const int w = tid >> 6, l = tid & 63;
    const int m = l & 15, q = l >> 4;
    const int b0 = blockIdx.x * 16;

    constexpr double CBRT2 = 1.2599210498948731647672106072782;
    constexpr double W1c = 1.0 / (2.0 - CBRT2);
    constexpr double W0c = -CBRT2 * W1c;
    constexpr double DTd = 0.01;
    constexpr double D1 = W1c, D2 = W0c, D3 = W1c;
    constexpr double C2c = (W0c + W1c) * 0.5, C4c = W1c * 0.5;
    constexpr double E1 = (C2c + C2c + C4c) * D1;
    constexpr double E2 = (C2c + C4c) * D2;
    constexpr double E3 = C4c * D3;
    const float dtf = (float)DTd, dt2 = (float)(DTd * DTd);
    const float se = (float)(E1 + E2 + E3);

    // --- phase 1: hT = U vT, gT = U fT; all operands straight from global ---
    // B-frag: lane l covers (col = b0+(l&15), k = p*32+(l>>4)*8+j) -> 32B load
    const float* vsrc = v_in  + (size_t)(b0 + m) * DD + q * 8;
    const float* fsrc = force + (size_t)(b0 + m) * DD + q * 8;
    const uchar* const up = ws + U_OFF + ((size_t)(w * 32) << 10) + l * 16;

    uint4v ub[4];
    #pragma unroll
    for (int p = 0; p < 4; ++p)
        ub[p] = *reinterpret_cast<const uint4v*>(up + ((size_t)p << 10));

    f32x4 h = {0.f, 0.f, 0.f, 0.f}, g = {0.f, 0.f, 0.f, 0.f};
    #pragma unroll
    for (int p = 0; p < 32; ++p) {
        const uint4v uc = ub[p & 3];
        if (p < 28)
            ub[p & 3] = *reinterpret_cast<const uint4v*>(up + ((size_t)(p + 4) << 10));
        const float4 v0 = *reinterpret_cast<const float4*>(vsrc + p * 32);
        const float4 v1 = *reinterpret_cast<const float4*>(vsrc + p * 32 + 4);
        const float4 f0 = *reinterpret_cast<const float4*>(fsrc + p * 32);
        const float4 f1 = *reinterpret_cast<const float4*>(fsrc + p * 32 + 4);
        const short8 ua = __builtin_bit_cast(short8, uc);
        const short8 va = __builtin_bit_cast(short8, frag8(v0, v1));
        const short8 fa = __builtin_bit_cast(short8, frag8(f0, f1));
        h = __builtin_amdgcn_mfma_f32_16x16x32_bf16(ua, va, h, 0, 0, 0);
        g = __builtin_amdgcn_mfma_f32_16x16x32_bf16(ua, fa, g, 0, 0, 0);
    }

    // --- phase 2 setup: lane's 4 R-rows k0..k0+3; h2 frag coords ------------
    const int k0 = 16 * w + 4 * q;
    const int p0 = k0 >> 5;
    const int lp = ((k0 & 31) >> 3) * 16 + m;
    const int j0 = k0 & 7;
    uchar* const h2w0 = H2B + (size_t)p0 * 1024 + lp * 16 + j0 * 2;

    f32x4 P, Q;
    {   // s = 0
        float h2[4];
        #pragma unroll
        for (int i = 0; i < 4; ++i) h2[i] = h[i] * h[i];
        #pragma unroll
        for (int i = 0; i < 4; ++i) {
            P[i] = (float)D1 * h2[i];
            Q[i] = (float)E1 * h2[i];
        }
        *reinterpret_cast<uint*>(h2w0)     = f2bf2(h2[0], h2[1]);
        *reinterpret_cast<uint*>(h2w0 + 4) = f2bf2(h2[2], h2[3]);
    }

    // M frags: wave w's 8 slices from global (L2-broadcast), resident for
    // BOTH phase-2 GEMMs (32 VGPRs)
    const uchar* const mp = ws + M_OFF + ((size_t)(w * 8) << 10) + l * 16;
    uint4v mb[8];
    #pragma unroll
    for (int p = 0; p < 8; ++p)
        mb[p] = *reinterpret_cast<const uint4v*>(mp + ((size_t)p << 10));

    __syncthreads();   // B1: H2B[s=0] ready
    {
        f32x4 acc = {0.f, 0.f, 0.f, 0.f};
        #pragma unroll
        for (int p = 0; p < 8; ++p) {
            const short8 hb = __builtin_bit_cast(short8,
                *reinterpret_cast<const uint4v*>(H2B + ((size_t)p << 10) + l * 16));
            acc = __builtin_amdgcn_mfma_f32_16x16x32_bf16(
                      __builtin_bit_cast(short8, mb[p]), hb, acc, 0, 0, 0);
        }
        const float cg = (float)(DTd * D1);
        #pragma unroll
        for (int i = 0; i < 4; ++i) h[i] += cg * (g[i] - acc[i]);
    }
    __syncthreads();   // B2: all s=0 H2B reads done
    {   // s = 1
        float h2[4];
        #pragma unroll
        for (int i = 0; i < 4; ++i) h2[i] = h[i] * h[i];
        #pragma unroll
        for (int i = 0; i < 4; ++i) {
            P[i] += (float)D2 * h2[i];
            Q[i] += (float)E2 * h2[i];
        }
        *reinterpret_cast<uint*>(h2w0)     = f2bf2(h2[0], h2[1]);
        *reinterpret_cast<uint*>(h2w0 + 4) = f2bf2(h2[2], h2[3]);
    }
    __syncthreads();   // B3: H2B[s=1] ready
    {
        f32x4 acc = {0.f, 0.f, 0.f, 0.f};
        #pragma unroll
        for (int p = 0; p < 8; ++p) {
            const short8 hb = __builtin_bit_cast(short8,
                *reinterpret_cast<const uint4v*>(H2B + ((size_t)p << 10) + l * 16));
            acc = __builtin_amdgcn_mfma_f32_16x16x32_bf16(
                      __builtin_bit_cast(short8, mb[p]), hb, acc, 0, 0, 0);
        }
        const float cg = (float)(DTd * D2);
        #pragma unroll
        for (int i = 0; i < 4; ++i) h[i] += cg * (g[i] - acc[i]);
    }
    {   // s = 2: accumulate only
        float h2[4];
        #pragma unroll
        for (int i = 0; i < 4; ++i) h2[i] = h[i] * h[i];
        #pragma unroll
        for (int i = 0; i < 4; ++i) {
            P[i] += (float)D3 * h2[i];
            Q[i] += (float)E3 * h2[i];
        }
    }
    // publish P, Q as bf16 B-frags
    *reinterpret_cast<uint*>(PB + (size_t)p0 * 1024 + lp * 16 + j0 * 2)     = f2bf2(P[0], P[1]);
    *reinterpret_cast<uint*>(PB + (size_t)p0 * 1024 + lp * 16 + j0 * 2 + 4) = f2bf2(P[2], P[3]);
    *reinterpret_cast<uint*>(QB + (size_t)p0 * 1024 + lp * 16 + j0 * 2)     = f2bf2(Q[0], Q[1]);
    *reinterpret_cast<uint*>(QB + (size_t)p0 * 1024 + lp * 16 + j0 * 2 + 4) = f2bf2(Q[2], Q[3]);

    // --- phase 3 W prefetch (tiles 4w, 4w+1; 4-deep), flies over barrier ----
    const uchar* const wpb = ws + W_OFF + l * 16;
    uint4v wb[4][2];
    #pragma unroll
    for (int p = 0; p < 4; ++p) {
        wb[p][0] = *reinterpret_cast<const uint4v*>(wpb + (size_t)((4 * w)     * 8 + p) * 1024);
        wb[p][1] = *reinterpret_cast<const uint4v*>(wpb + (size_t)((4 * w + 1) * 8 + p) * 1024);
    }

    __syncthreads();   // B4: PB/QB ready

    // --- phase 3: GammaV^T = W P^T, GammaX^T = W Q^T + fused epilogue -------
    #pragma unroll
    for (int half = 0; half < 2; ++half) {
        const int t0 = 4 * w + half * 2;
        f32x4 aV[2] = {{0.f,0.f,0.f,0.f}, {0.f,0.f,0.f,0.f}};
        f32x4 aX[2] = {{0.f,0.f,0.f,0.f}, {0.f,0.f,0.f,0.f}};
        #pragma unroll
        for (int p = 0; p < 8; ++p) {
            const uint4v c0 = wb[p & 3][0];
            const uint4v c1 = wb[p & 3][1];
            if (p < 4) {            // this half's slices p+4
                wb[p & 3][0] = *reinterpret_cast<const uint4v*>(
                    wpb + (size_t)((t0)     * 8 + p + 4) * 1024);
                wb[p & 3][1] = *reinterpret_cast<const uint4v*>(
                    wpb + (size_t)((t0 + 1) * 8 + p + 4) * 1024);
            } else if (half == 0) { // next half's slices p-4
                wb[p & 3][0] = *reinterpret_cast<const uint4v*>(
                    wpb + (size_t)((t0 + 2) * 8 + (p - 4)) * 1024);
                wb[p & 3][1] = *reinterpret_cast<const uint4v*>(
                    wpb + (size_t)((t0 + 3) * 8 + (p - 4)) * 1024);
            }
            const short8 pb = __builtin_bit_cast(short8,
                *reinterpret_cast<const uint4v*>(PB + ((size_t)p << 10) + l * 16));
            const short8 qb = __builtin_bit_cast(short8,
                *reinterpret_cast<const uint4v*>(QB + ((size_t)p << 10) + l * 16));
            const short8 w0 = __builtin_bit_cast(short8, c0);
            const short8 w1 = __builtin_bit_cast(short8, c1);
            aV[0] = __builtin_amdgcn_mfma_f32_16x16x32_bf16(w0, pb, aV[0], 0, 0, 0);
            aV[1] = __builtin_amdgcn_mfma_f32_16x16x32_bf16(w1, pb, aV[1], 0, 0, 0);
            aX[0] = __builtin_amdgcn_mfma_f32_16x16x32_bf16(w0, qb, aX[0], 0, 0, 0);
            aX[1] = __builtin_amdgcn_mfma_f32_16x16x32_bf16(w1, qb, aX[1], 0, 0, 0);
        }
        // epilogue: lane holds (batch b0+m, D = (t0+t)*16 + 4q + i), f32 exact
        #pragma unroll
        for (int t = 0; t < 2; ++t) {
            const size_t gib = (size_t)(b0 + m) * DD + (t0 + t) * 16 + 4 * q;
            const float4 fv = *reinterpret_cast<const float4*>(force + gib);
            const float4 v0 = *reinterpret_cast<const float4*>(v_in + gib);
            const float4 x0 = *reinterpret_cast<const float4*>(x_in + gib);
            float4 vo, xo;
            vo.x = v0.x + dtf * fv.x - dtf * aV[t][0];
            vo.y = v0.y + dtf * fv.y - dtf * aV[t][1];
            vo.z = v0.z + dtf * fv.z - dtf * aV[t][2];
            vo.w = v0.w + dtf * fv.w - dtf * aV[t][3];
            xo.x = x0.x + dtf * v0.x + dt2 * se * fv.x - dt2 * aX[t][0];
            xo.y = x0.y + dtf * v0.y + dt2 * se * fv.y - dt2 * aX[t][1];
            xo.z = x0.z + dtf * v0.z + dt2 * se * fv.z - dt2 * aX[t][2];
            xo.w = x0.w + dtf * v0.w + dt2 * se * fv.w - dt2 * aX[t][3];
            *reinterpret_cast<float4*>(v_out + gib) = vo;
            *reinterpret_cast<float4*>(x_out + gib) = xo;
        }
    }
}

extern "C" void kernel_launch(void* const* d_in, const int* in_sizes, int n_in,
                              void* d_out, int out_size, void* d_ws, size_t ws_size,
                              hipStream_t stream) {
    const float* x     = (const float*)d_in[0];
    const float* v     = (const float*)d_in[1];
    const float* force = (const float*)d_in[2];
    const float* U     = (const float*)d_in[3];
    const float* W     = (const float*)d_in[4];

    float* x_out = (float*)d_out;
    float* v_out = x_out + (size_t)BSZ * DD;

    uchar* ws = (uchar*)d_ws;   // 1.125MB: U/W/M bf16 frags

    pack_kernel<<<dim3(192), dim3(256), 0, stream>>>(U, W, ws);
    mm_kernel<<<dim3(64), dim3(1024), 0, stream>>>(U, W, ws);
    yoshida_fused_kernel<<<dim3(BSZ / 16), dim3(1024), 0, stream>>>(
        x, v, force, ws, x_out, v_out);
}

// Round 8
// 147.952 us; speedup vs baseline: 1.6409x; 1.6409x over previous
//
#include <hip/hip_runtime.h>

// Yoshida 4th-order integrator, Gamma(v) = W @ (U v)^2, B=4096, D=1024, R=256.
// R14: R12-staged R-space algorithm minus its serial phases.
// Evidence: bench total = ~86us harness fills + sum(our kernels); R12=53.5
// fused (LDS-staged, phase-serialized), R13=93 (de-staged phase 1 exposed
// global latency -> every non-prefetched global load costs full latency) and
// its 64-block mm ~60us. So: KEEP vA/fA LDS staging (R12, proven), REMOVE the
// M LDS stage (M -> 32 VGPRs, loads issued between phase-1 end and B1 so they
// fly over the barrier; L2-broadcast, off critical path), REMOVE one barrier
// (dual H2B0/H2B1 buffers: 4 barriers total), keep R13's float4 epilogue,
// merge pack+mm into one 448-block prep kernel (mm at 256 blocks, 8 partial
// accumulators, every CU busy, atomic-free bf16-frag output).
// Numerics = R13 exactly (passed, absmax 0.1): bf16 frags everywhere, f32 h/P/Q
// state, f32 epilogue.

#define BSZ 4096
#define DD 1024
#define RR 256

// ws layout (1.125MB)
#define U_OFF 0u                  // 512KB bf16 U A-frags: (nt*32+p)*1024 + l*16
#define W_OFF (512u * 1024u)      // 512KB bf16 W A-frags: (dt*8+p)*1024 + l*16
#define M_OFF (1024u * 1024u)     // 128KB bf16 M A-frags: (nt*8+p)*1024 + l*16

typedef unsigned char uchar;
typedef unsigned int uint;
typedef unsigned short ushort;
typedef __attribute__((ext_vector_type(4))) float f32x4;
typedef __attribute__((ext_vector_type(4))) uint uint4v;
typedef __attribute__((ext_vector_type(8))) short short8;

__device__ inline uint f2bf1(float x) {
    uint u = __builtin_bit_cast(uint, x);
    return (u + 0x7FFFu + ((u >> 16) & 1u)) >> 16;     // RNE f32->bf16
}
__device__ inline uint f2bf2(float lo, float hi) {
    return f2bf1(lo) | (f2bf1(hi) << 16);
}
// HW conversion path: compiler lowers __bf16 casts to v_cvt_pk_bf16_f32
__device__ inline uint cvt2(float a, float b) {
    const __bf16 lo = (__bf16)a, hi = (__bf16)b;
    return (uint)__builtin_bit_cast(ushort, lo) |
           ((uint)__builtin_bit_cast(ushort, hi) << 16);
}
__device__ inline uint4v frag8(const float4 a, const float4 b) {
    uint4v o;
    o.x = cvt2(a.x, a.y); o.y = cvt2(a.z, a.w);
    o.z = cvt2(b.x, b.y); o.w = cvt2(b.z, b.w);
    return o;
}

// ---- prep: pack U/W bf16 A-frags (blocks 0..191) + M = U@W (blocks 192..447)
// Fragment: slice(tile,p) = 1KB; lane l holds row=(l&15), k=p*32+(l>>4)*8+j.
__global__ __launch_bounds__(256) void prep_kernel(
    const float* __restrict__ U, const float* __restrict__ W,
    uchar* __restrict__ ws)
{
    if (blockIdx.x < 192) {             // ---- pack U and W frags ----
        const int g = blockIdx.x * 256 + threadIdx.x;   // 0..49151
        const int l = g & 63;
        const float* src;
        size_t dst;
        if (g < 32768) {                // U: 16 nt x 32 p slices
            const int slice = g >> 6, nt = slice >> 5, p = slice & 31;
            src = U + (size_t)(nt * 16 + (l & 15)) * DD + p * 32 + (l >> 4) * 8;
            dst = U_OFF + (size_t)slice * 1024 + l * 16;
        } else {                        // W: 64 dt x 8 p slices
            const int g2 = g - 32768;
            const int slice = g2 >> 6, dt_ = slice >> 3, p = slice & 7;
            src = W + (size_t)(dt_ * 16 + (l & 15)) * RR + p * 32 + (l >> 4) * 8;
            dst = W_OFF + (size_t)slice * 1024 + l * 16;
        }
        const float4 a0 = *reinterpret_cast<const float4*>(src);
        const float4 a1 = *reinterpret_cast<const float4*>(src + 4);
        uint4v o;
        o.x = f2bf2(a0.x, a0.y); o.y = f2bf2(a0.z, a0.w);
        o.z = f2bf2(a1.x, a1.y); o.w = f2bf2(a1.z, a1.w);
        *reinterpret_cast<uint4v*>(ws + dst) = o;
    } else {                            // ---- M = U @ W, bf16 frag out ----
        const int bid = blockIdx.x - 192;        // 0..255
        const int rt = bid >> 4, ct = bid & 15;  // 16x16 output tile
        const int r = rt * 16 + (threadIdx.x >> 4);
        const int c = ct * 16 + (threadIdx.x & 15);
        const float* ur = U + (size_t)r * DD;
        const float* wc = W + c;
        float acc[8];
        #pragma unroll
        for (int i = 0; i < 8; ++i) acc[i] = 0.f;
        #pragma unroll 4
        for (int k = 0; k < DD; k += 8) {
            const float4 u0 = *reinterpret_cast<const float4*>(ur + k);
            const float4 u1 = *reinterpret_cast<const float4*>(ur + k + 4);
            acc[0] += u0.x * wc[(size_t)(k + 0) * RR];
            acc[1] += u0.y * wc[(size_t)(k + 1) * RR];
            acc[2] += u0.z * wc[(size_t)(k + 2) * RR];
            acc[3] += u0.w * wc[(size_t)(k + 3) * RR];
            acc[4] += u1.x * wc[(size_t)(k + 4) * RR];
            acc[5] += u1.y * wc[(size_t)(k + 5) * RR];
            acc[6] += u1.z * wc[(size_t)(k + 6) * RR];
            acc[7] += u1.w * wc[(size_t)(k + 7) * RR];
        }
        const float s = ((acc[0] + acc[1]) + (acc[2] + acc[3]))
                      + ((acc[4] + acc[5]) + (acc[6] + acc[7]));
        // frag address for element (row r, k=c) — verified in R13 (passed)
        const int slice = ((r >> 4) << 3) + (c >> 5);
        const int ll = (r & 15) | (((c >> 3) & 3) << 4);
        *reinterpret_cast<ushort*>(
            ws + M_OFF + (size_t)slice * 1024 + ll * 16 + (c & 7) * 2)
            = (ushort)f2bf1(s);
    }
}

// ---- fused integrator ------------------------------------------------------
__global__ __launch_bounds__(1024) void yoshida_fused_kernel(
    const float* __restrict__ x_in,
    const float* __restrict__ v_in,
    const float* __restrict__ force,
    const uchar* __restrict__ ws,
    float* __restrict__ x_out,
    float* __restrict__ v_out)
{
    __shared__ __align__(16) uchar vA[32768];    // v bf16 B-frags, 32 slices
    __shared__ __align__(16) uchar fA[32768];    // f bf16 B-frags
    __shared__ __align__(16) uchar H2B0[8192];   // h2(s=0) B-frags
    __shared__ __align__(16) uchar H2B1[8192];   // h2(s=1) B-frags
    __shared__ __align__(16) uchar PB[8192];     // P B-frags
    __shared__ __align__(16) uchar QB[8192];     // Q B-frags

    const int tid = threadIdx.x;
    const int w = tid >> 6, l = tid & 63;
    const int m = l & 15, q = l >> 4;
    const int b0 = blockIdx.x * 16;

    constexpr double CBRT2 = 1.2599210498948731647672106072782;
    constexpr double W1c = 1.0 / (2.0 - CBRT2);
    constexpr double W0c = -CBRT2 * W1c;
    constexpr double DTd = 0.01;
    constexpr double D1 = W1c, D2 = W0c, D3 = W1c;
    constexpr double C2c = (W0c + W1c) * 0.5, C4c = W1c * 0.5;
    constexpr double E1 = (C2c + C2c + C4c) * D1;
    constexpr double E2 = (C2c + C4c) * D2;
    constexpr double E3 = C4c * D3;
    const float dtf = (float)DTd, dt2 = (float)(DTd * DTd);
    const float se = (float)(E1 + E2 + E3);

    // --- stage vA/fA as bf16 B-frags (wave w -> slices 2w, 2w+1) ------------
    #pragma unroll
    for (int j = 0; j < 2; ++j) {
        const int p = 2 * w + j;
        const size_t so = (size_t)(b0 + m) * DD + p * 32 + q * 8;
        const float4 v0_ = *reinterpret_cast<const float4*>(v_in + so);
        const float4 v1_ = *reinterpret_cast<const float4*>(v_in + so + 4);
        const float4 f0_ = *reinterpret_cast<const float4*>(force + so);
        const float4 f1_ = *reinterpret_cast<const float4*>(force + so + 4);
        *reinterpret_cast<uint4v*>(vA + (size_t)p * 1024 + l * 16) = frag8(v0_, v1_);
        *reinterpret_cast<uint4v*>(fA + (size_t)p * 1024 + l * 16) = frag8(f0_, f1_);
    }

    // --- U ring prefetch 8-deep (flies over B0) -----------------------------
    const uchar* const up = ws + U_OFF + ((size_t)(w * 32) << 10) + l * 16;
    uint4v ub[8];
    #pragma unroll
    for (int p = 0; p < 8; ++p)
        ub[p] = *reinterpret_cast<const uint4v*>(up + ((size_t)p << 10));

    __syncthreads();   // B0: vA/fA staged

    // --- phase 1: hT = U vT, gT = U fT (shared U stream, LDS B-frags) -------
    f32x4 h = {0.f, 0.f, 0.f, 0.f}, g = {0.f, 0.f, 0.f, 0.f};
    #pragma unroll
    for (int p = 0; p < 32; ++p) {
        const uint4v uc = ub[p & 7];
        if (p < 24)
            ub[p & 7] = *reinterpret_cast<const uint4v*>(up + ((size_t)(p + 8) << 10));
        const short8 ua = __builtin_bit_cast(short8, uc);
        const short8 va = __builtin_bit_cast(short8,
            *reinterpret_cast<const uint4v*>(vA + ((size_t)p << 10) + l * 16));
        const short8 fa = __builtin_bit_cast(short8,
            *reinterpret_cast<const uint4v*>(fA + ((size_t)p << 10) + l * 16));
        h = __builtin_amdgcn_mfma_f32_16x16x32_bf16(ua, va, h, 0, 0, 0);
        g = __builtin_amdgcn_mfma_f32_16x16x32_bf16(ua, fa, g, 0, 0, 0);
    }

    // --- M frags -> 32 VGPRs (issued here so they fly over B1; L2-broadcast)
    const uchar* const mp = ws + M_OFF + ((size_t)(w * 8) << 10) + l * 16;
    uint4v mb[8];
    #pragma unroll
    for (int p = 0; p < 8; ++p)
        mb[p] = *reinterpret_cast<const uint4v*>(mp + ((size_t)p << 10));

    // --- phase 2: lane's 4 R-rows k0..k0+3; h2 frag coords ------------------
    const int k0 = 16 * w + 4 * q;
    const int p0 = k0 >> 5;
    const int lp = ((k0 & 31) >> 3) * 16 + m;
    const int j0 = k0 & 7;
    const int hoff = p0 * 1024 + lp * 16 + j0 * 2;

    f32x4 P, Q;
    {   // s = 0
        float h2[4];
        #pragma unroll
        for (int i = 0; i < 4; ++i) h2[i] = h[i] * h[i];
        #pragma unroll
        for (int i = 0; i < 4; ++i) {
            P[i] = (float)D1 * h2[i];
            Q[i] = (float)E1 * h2[i];
        }
        *reinterpret_cast<uint*>(H2B0 + hoff)     = f2bf2(h2[0], h2[1]);
        *reinterpret_cast<uint*>(H2B0 + hoff + 4) = f2bf2(h2[2], h2[3]);
    }

    __syncthreads();   // B1: H2B0 ready
    {   // GEMM1: acc = M h2_0
        f32x4 acc = {0.f, 0.f, 0.f, 0.f};
        #pragma unroll
        for (int p = 0; p < 8; ++p) {
            const short8 hb = __builtin_bit_cast(short8,
                *reinterpret_cast<const uint4v*>(H2B0 + ((size_t)p << 10) + l * 16));
            acc = __builtin_amdgcn_mfma_f32_16x16x32_bf16(
                      __builtin_bit_cast(short8, mb[p]), hb, acc, 0, 0, 0);
        }
        const float cg = (float)(DTd * D1);
        #pragma unroll
        for (int i = 0; i < 4; ++i) h[i] += cg * (g[i] - acc[i]);
    }
    {   // s = 1 -> H2B1 (double buffer: no barrier needed before the write)
        float h2[4];
        #pragma unroll
        for (int i = 0; i < 4; ++i) h2[i] = h[i] * h[i];
        #pragma unroll
        for (int i = 0; i < 4; ++i) {
            P[i] += (float)D2 * h2[i];
            Q[i] += (float)E2 * h2[i];
        }
        *reinterpret_cast<uint*>(H2B1 + hoff)     = f2bf2(h2[0], h2[1]);
        *reinterpret_cast<uint*>(H2B1 + hoff + 4) = f2bf2(h2[2], h2[3]);
    }
    __syncthreads();   // B3: H2B1 ready
    {   // GEMM2: acc = M h2_1
        f32x4 acc = {0.f, 0.f, 0.f, 0.f};
        #pragma unroll
        for (int p = 0; p < 8; ++p) {
            const short8 hb = __builtin_bit_cast(short8,
                *reinterpret_cast<const uint4v*>(H2B1 + ((size_t)p << 10) + l * 16));
            acc = __builtin_amdgcn_mfma_f32_16x16x32_bf16(
                      __builtin_bit_cast(short8, mb[p]), hb, acc, 0, 0, 0);
        }
        const float cg = (float)(DTd * D2);
        #pragma unroll
        for (int i = 0; i < 4; ++i) h[i] += cg * (g[i] - acc[i]);
    }
    {   // s = 2: accumulate only
        float h2[4];
        #pragma unroll
        for (int i = 0; i < 4; ++i) h2[i] = h[i] * h[i];
        #pragma unroll
        for (int i = 0; i < 4; ++i) {
            P[i] += (float)D3 * h2[i];
            Q[i] += (float)E3 * h2[i];
        }
    }
    // publish P, Q as bf16 B-frags
    *reinterpret_cast<uint*>(PB + hoff)     = f2bf2(P[0], P[1]);
    *reinterpret_cast<uint*>(PB + hoff + 4) = f2bf2(P[2], P[3]);
    *reinterpret_cast<uint*>(QB + hoff)     = f2bf2(Q[0], Q[1]);
    *reinterpret_cast<uint*>(QB + hoff + 4) = f2bf2(Q[2], Q[3]);

    // --- phase 3 W prefetch (tiles 4w, 4w+1; 4-deep), flies over barrier ----
    const uchar* const wpb = ws + W_OFF + l * 16;
    uint4v wb[4][2];
    #pragma unroll
    for (int p = 0; p < 4; ++p) {
        wb[p][0] = *reinterpret_cast<const uint4v*>(wpb + (size_t)((4 * w)     * 8 + p) * 1024);
        wb[p][1] = *reinterpret_cast<const uint4v*>(wpb + (size_t)((4 * w + 1) * 8 + p) * 1024);
    }

    __syncthreads();   // B5: PB/QB ready

    // --- phase 3: GammaV^T = W P^T, GammaX^T = W Q^T + fused f32 epilogue ---
    #pragma unroll
    for (int half = 0; half < 2; ++half) {
        const int t0 = 4 * w + half * 2;
        f32x4 aV[2] = {{0.f,0.f,0.f,0.f}, {0.f,0.f,0.f,0.f}};
        f32x4 aX[2] = {{0.f,0.f,0.f,0.f}, {0.f,0.f,0.f,0.f}};
        #pragma unroll
        for (int p = 0; p < 8; ++p) {
            const uint4v c0 = wb[p & 3][0];
            const uint4v c1 = wb[p & 3][1];
            if (p < 4) {            // this half's slices p+4
                wb[p & 3][0] = *reinterpret_cast<const uint4v*>(
                    wpb + (size_t)((t0)     * 8 + p + 4) * 1024);
                wb[p & 3][1] = *reinterpret_cast<const uint4v*>(
                    wpb + (size_t)((t0 + 1) * 8 + p + 4) * 1024);
            } else if (half == 0) { // next half's slices p-4
                wb[p & 3][0] = *reinterpret_cast<const uint4v*>(
                    wpb + (size_t)((t0 + 2) * 8 + (p - 4)) * 1024);
                wb[p & 3][1] = *reinterpret_cast<const uint4v*>(
                    wpb + (size_t)((t0 + 3) * 8 + (p - 4)) * 1024);
            }
            const short8 pb = __builtin_bit_cast(short8,
                *reinterpret_cast<const uint4v*>(PB + ((size_t)p << 10) + l * 16));
            const short8 qb = __builtin_bit_cast(short8,
                *reinterpret_cast<const uint4v*>(QB + ((size_t)p << 10) + l * 16));
            const short8 w0 = __builtin_bit_cast(short8, c0);
            const short8 w1 = __builtin_bit_cast(short8, c1);
            aV[0] = __builtin_amdgcn_mfma_f32_16x16x32_bf16(w0, pb, aV[0], 0, 0, 0);
            aV[1] = __builtin_amdgcn_mfma_f32_16x16x32_bf16(w1, pb, aV[1], 0, 0, 0);
            aX[0] = __builtin_amdgcn_mfma_f32_16x16x32_bf16(w0, qb, aX[0], 0, 0, 0);
            aX[1] = __builtin_amdgcn_mfma_f32_16x16x32_bf16(w1, qb, aX[1], 0, 0, 0);
        }
        // epilogue: lane holds (batch b0+m, D = (t0+t)*16 + 4q + i), f32 exact
        #pragma unroll
        for (int t = 0; t < 2; ++t) {
            const size_t gib = (size_t)(b0 + m) * DD + (t0 + t) * 16 + 4 * q;
            const float4 fv = *reinterpret_cast<const float4*>(force + gib);
            const float4 v0 = *reinterpret_cast<const float4*>(v_in + gib);
            const float4 x0 = *reinterpret_cast<const float4*>(x_in + gib);
            float4 vo, xo;
            vo.x = v0.x + dtf * fv.x - dtf * aV[t][0];
            vo.y = v0.y + dtf * fv.y - dtf * aV[t][1];
            vo.z = v0.z + dtf * fv.z - dtf * aV[t][2];
            vo.w = v0.w + dtf * fv.w - dtf * aV[t][3];
            xo.x = x0.x + dtf * v0.x + dt2 * se * fv.x - dt2 * aX[t][0];
            xo.y = x0.y + dtf * v0.y + dt2 * se * fv.y - dt2 * aX[t][1];
            xo.z = x0.z + dtf * v0.z + dt2 * se * fv.z - dt2 * aX[t][2];
            xo.w = x0.w + dtf * v0.w + dt2 * se * fv.w - dt2 * aX[t][3];
            *reinterpret_cast<float4*>(v_out + gib) = vo;
            *reinterpret_cast<float4*>(x_out + gib) = xo;
        }
    }
}

extern "C" void kernel_launch(void* const* d_in, const int* in_sizes, int n_in,
                              void* d_out, int out_size, void* d_ws, size_t ws_size,
                              hipStream_t stream) {
    const float* x     = (const float*)d_in[0];
    const float* v     = (const float*)d_in[1];
    const float* force = (const float*)d_in[2];
    const float* U     = (const float*)d_in[3];
    const float* W     = (const float*)d_in[4];

    float* x_out = (float*)d_out;
    float* v_out = x_out + (size_t)BSZ * DD;

    uchar* ws = (uchar*)d_ws;   // 1.125MB: U/W/M bf16 frags

    prep_kernel<<<dim3(448), dim3(256), 0, stream>>>(U, W, ws);
    yoshida_fused_kernel<<<dim3(BSZ / 16), dim3(1024), 0, stream>>>(
        x, v, force, ws, x_out, v_out);
}

// Round 9
// 139.700 us; speedup vs baseline: 1.7378x; 1.0591x over previous
//
#include <hip/hip_runtime.h>

// Yoshida 4th-order integrator, Gamma(v) = W @ (U v)^2, B=4096, D=1024, R=256.
// R15: split R14's fused kernel at the h/g seam + MFMA-based mm prep.
// Evidence: bench = ~80us harness fills + sum(kernels). R14: fused 46.5 but
// merged prep ~20us (strided scalar mm). Fused floor analysis: phase 1 forces
// 1MB LDS traffic/CU (16 waves re-read 64KB vA/fA), 98KB LDS -> 1 block/CU,
// epilogue HBM burst serialized behind 4 barriers.
// K1 (hg): 256 x 512thr, 8 waves x 2 n-tiles/wave -> each ds_read feeds 2
//   MFMAs (LDS traffic halved), 4 indep MFMA chains, h/g f32 -> ws (8MB).
// K2 (iter): 512 blocks (256 btile x 2 d-half) x 1024thr, LDS 32KB -> 2
//   blocks/CU; h/g float4 per-lane loads; M in 32 VGPRs; phase2 duplicated
//   per half (trivial, L2-warm); phase3 + f32 epilogue on own d-half.
// mm: 64 x 256 MFMA (A = packed U frags, B = 8 strided W loads/lane) ~2us.
// Numerics identical to R13/R14 (passed, absmax 0.1025).

#define BSZ 4096
#define DD 1024
#define RR 256

// ws layout (10MB of >=256MB)
#define U_OFF 0u                   // 512KB bf16 U A-frags: (nt*32+p)*1024+l*16
#define W_OFF (512u * 1024u)       // 512KB bf16 W A-frags: (dt*8+p)*1024+l*16
#define M_OFF (1024u * 1024u)      // 128KB bf16 M A-frags: (rt*8+p)*1024+l*16
#define H_OFF (2u * 1024u * 1024u) // 4MB f32 H[4096][256]
#define G_OFF (6u * 1024u * 1024u) // 4MB f32 G[4096][256]

typedef unsigned char uchar;
typedef unsigned int uint;
typedef unsigned short ushort;
typedef __attribute__((ext_vector_type(4))) float f32x4;
typedef __attribute__((ext_vector_type(4))) uint uint4v;
typedef __attribute__((ext_vector_type(8))) short short8;

__device__ inline uint f2bf1(float x) {
    uint u = __builtin_bit_cast(uint, x);
    return (u + 0x7FFFu + ((u >> 16) & 1u)) >> 16;     // RNE f32->bf16
}
__device__ inline uint f2bf2(float lo, float hi) {
    return f2bf1(lo) | (f2bf1(hi) << 16);
}
__device__ inline uint cvt2(float a, float b) {       // HW v_cvt_pk_bf16_f32
    const __bf16 lo = (__bf16)a, hi = (__bf16)b;
    return (uint)__builtin_bit_cast(ushort, lo) |
           ((uint)__builtin_bit_cast(ushort, hi) << 16);
}
__device__ inline uint4v frag8(const float4 a, const float4 b) {
    uint4v o;
    o.x = cvt2(a.x, a.y); o.y = cvt2(a.z, a.w);
    o.z = cvt2(b.x, b.y); o.w = cvt2(b.z, b.w);
    return o;
}

// ---- pack U and W into bf16 fragment-major A-frags (layout verified R13/14)
__global__ __launch_bounds__(256) void pack_kernel(
    const float* __restrict__ U, const float* __restrict__ W,
    uchar* __restrict__ ws)
{
    const int g = blockIdx.x * 256 + threadIdx.x;       // 0..49151
    const int l = g & 63;
    const float* src;
    size_t dst;
    if (g < 32768) {                 // U: 16 nt x 32 p slices
        const int slice = g >> 6, nt = slice >> 5, p = slice & 31;
        src = U + (size_t)(nt * 16 + (l & 15)) * DD + p * 32 + (l >> 4) * 8;
        dst = U_OFF + (size_t)slice * 1024 + l * 16;
    } else {                         // W: 64 dt x 8 p slices
        const int g2 = g - 32768;
        const int slice = g2 >> 6, dt_ = slice >> 3, p = slice & 7;
        src = W + (size_t)(dt_ * 16 + (l & 15)) * RR + p * 32 + (l >> 4) * 8;
        dst = W_OFF + (size_t)slice * 1024 + l * 16;
    }
    const float4 a0 = *reinterpret_cast<const float4*>(src);
    const float4 a1 = *reinterpret_cast<const float4*>(src + 4);
    uint4v o;
    o.x = f2bf2(a0.x, a0.y); o.y = f2bf2(a0.z, a0.w);
    o.z = f2bf2(a1.x, a1.y); o.w = f2bf2(a1.z, a1.w);
    *reinterpret_cast<uint4v*>(ws + dst) = o;
}

// ---- M = U @ W via MFMA: 64 blocks x 4 waves; wave = one (rt, ct) 16x16 tile
// A = packed U frags (vector loads); B built from 8 strided W loads per lane.
__global__ __launch_bounds__(256) void mm_kernel(
    const float* __restrict__ W, uchar* __restrict__ ws)
{
    const int tid = threadIdx.x;
    const int wv = tid >> 6, l = tid & 63;
    const int m_ = l & 15, q = l >> 4;
    const int task = blockIdx.x * 4 + wv;      // 0..255
    const int rt = task >> 4, ct = task & 15;

    const uchar* ua_base = ws + U_OFF + ((size_t)(rt * 32) << 10) + l * 16;
    const float* wc = W + ct * 16 + m_;

    f32x4 acc = {0.f, 0.f, 0.f, 0.f};
    #pragma unroll 8
    for (int p = 0; p < 32; ++p) {
        const uint4v ua = *reinterpret_cast<const uint4v*>(ua_base + ((size_t)p << 10));
        const int dbase = p * 32 + q * 8;
        float w8[8];
        #pragma unroll
        for (int j = 0; j < 8; ++j) w8[j] = wc[(size_t)(dbase + j) * RR];
        uint4v bb;
        bb.x = cvt2(w8[0], w8[1]); bb.y = cvt2(w8[2], w8[3]);
        bb.z = cvt2(w8[4], w8[5]); bb.w = cvt2(w8[6], w8[7]);
        acc = __builtin_amdgcn_mfma_f32_16x16x32_bf16(
                  __builtin_bit_cast(short8, ua),
                  __builtin_bit_cast(short8, bb), acc, 0, 0, 0);
    }
    // write M[r][c] into A-frag layout (verified R13/R14)
    #pragma unroll
    for (int i = 0; i < 4; ++i) {
        const int r = rt * 16 + 4 * q + i;
        const int c = ct * 16 + m_;
        const int slice = ((r >> 4) << 3) + (c >> 5);
        const int ll = (r & 15) | (((c >> 3) & 3) << 4);
        *reinterpret_cast<ushort*>(
            ws + M_OFF + (size_t)slice * 1024 + ll * 16 + (c & 7) * 2)
            = (ushort)f2bf1(acc[i]);
    }
}

// ---- K1: h = U v, g = U f -> ws (f32). 8 waves x 2 n-tiles/wave ------------
__global__ __launch_bounds__(512) void hg_kernel(
    const float* __restrict__ v_in, const float* __restrict__ force,
    const uchar* __restrict__ ws, float* __restrict__ Hf, float* __restrict__ Gf)
{
    __shared__ __align__(16) uchar vA[32768];    // v bf16 B-frags, 32 slices
    __shared__ __align__(16) uchar fA[32768];    // f bf16 B-frags

    const int tid = threadIdx.x;
    const int w = tid >> 6, l = tid & 63;
    const int m = l & 15, q = l >> 4;
    const int b0 = blockIdx.x * 16;

    // stage vA/fA: 8 waves x 4 slices each
    #pragma unroll
    for (int j = 0; j < 4; ++j) {
        const int p = 4 * w + j;
        const size_t so = (size_t)(b0 + m) * DD + p * 32 + q * 8;
        const float4 v0 = *reinterpret_cast<const float4*>(v_in + so);
        const float4 v1 = *reinterpret_cast<const float4*>(v_in + so + 4);
        const float4 f0 = *reinterpret_cast<const float4*>(force + so);
        const float4 f1 = *reinterpret_cast<const float4*>(force + so + 4);
        *reinterpret_cast<uint4v*>(vA + (size_t)p * 1024 + l * 16) = frag8(v0, v1);
        *reinterpret_cast<uint4v*>(fA + (size_t)p * 1024 + l * 16) = frag8(f0, f1);
    }

    // U rings: 2 n-tile streams, 4-deep each (fly over the barrier)
    const uchar* const upA = ws + U_OFF + ((size_t)(64 * w) << 10) + l * 16;  // nt=2w
    const uchar* const upB = upA + (32u << 10);                               // nt=2w+1
    uint4v ubA[4], ubB[4];
    #pragma unroll
    for (int p = 0; p < 4; ++p) {
        ubA[p] = *reinterpret_cast<const uint4v*>(upA + ((size_t)p << 10));
        ubB[p] = *reinterpret_cast<const uint4v*>(upB + ((size_t)p << 10));
    }

    __syncthreads();   // vA/fA staged

    f32x4 hA = {0.f,0.f,0.f,0.f}, gA = {0.f,0.f,0.f,0.f};
    f32x4 hB = {0.f,0.f,0.f,0.f}, gB = {0.f,0.f,0.f,0.f};
    #pragma unroll
    for (int p = 0; p < 32; ++p) {
        const uint4v ucA = ubA[p & 3];
        const uint4v ucB = ubB[p & 3];
        if (p < 28) {
            ubA[p & 3] = *reinterpret_cast<const uint4v*>(upA + ((size_t)(p + 4) << 10));
            ubB[p & 3] = *reinterpret_cast<const uint4v*>(upB + ((size_t)(p + 4) << 10));
        }
        const short8 va = __builtin_bit_cast(short8,
            *reinterpret_cast<const uint4v*>(vA + ((size_t)p << 10) + l * 16));
        const short8 fa = __builtin_bit_cast(short8,
            *reinterpret_cast<const uint4v*>(fA + ((size_t)p << 10) + l * 16));
        hA = __builtin_amdgcn_mfma_f32_16x16x32_bf16(__builtin_bit_cast(short8, ucA), va, hA, 0, 0, 0);
        gA = __builtin_amdgcn_mfma_f32_16x16x32_bf16(__builtin_bit_cast(short8, ucA), fa, gA, 0, 0, 0);
        hB = __builtin_amdgcn_mfma_f32_16x16x32_bf16(__builtin_bit_cast(short8, ucB), va, hB, 0, 0, 0);
        gB = __builtin_amdgcn_mfma_f32_16x16x32_bf16(__builtin_bit_cast(short8, ucB), fa, gB, 0, 0, 0);
    }

    // store h,g: lane holds (batch b0+m, R rows k0..k0+3) per tile
    const int k0A = 32 * w + 4 * q;
    const size_t ho = (size_t)(b0 + m) * RR;
    *reinterpret_cast<f32x4*>(Hf + ho + k0A)      = hA;
    *reinterpret_cast<f32x4*>(Hf + ho + k0A + 16) = hB;
    *reinterpret_cast<f32x4*>(Gf + ho + k0A)      = gA;
    *reinterpret_cast<f32x4*>(Gf + ho + k0A + 16) = gB;
}

// ---- K2: R-space iteration + Gamma GEMMs + epilogue; 2 blocks/CU -----------
__global__ __launch_bounds__(1024) void iter_kernel(
    const float* __restrict__ x_in,
    const float* __restrict__ v_in,
    const float* __restrict__ force,
    const uchar* __restrict__ ws,
    const float* __restrict__ Hf, const float* __restrict__ Gf,
    float* __restrict__ x_out, float* __restrict__ v_out)
{
    __shared__ __align__(16) uchar H2B0[8192];
    __shared__ __align__(16) uchar H2B1[8192];
    __shared__ __align__(16) uchar PB[8192];
    __shared__ __align__(16) uchar QB[8192];

    const int tid = threadIdx.x;
    const int w = tid >> 6, l = tid & 63;
    const int m = l & 15, q = l >> 4;
    const int bt = blockIdx.x >> 1, dh = blockIdx.x & 1;
    const int b0 = bt * 16;

    constexpr double CBRT2 = 1.2599210498948731647672106072782;
    constexpr double W1c = 1.0 / (2.0 - CBRT2);
    constexpr double W0c = -CBRT2 * W1c;
    constexpr double DTd = 0.01;
    constexpr double D1 = W1c, D2 = W0c, D3 = W1c;
    constexpr double C2c = (W0c + W1c) * 0.5, C4c = W1c * 0.5;
    constexpr double E1 = (C2c + C2c + C4c) * D1;
    constexpr double E2 = (C2c + C4c) * D2;
    constexpr double E3 = C4c * D3;
    const float dtf = (float)DTd, dt2 = (float)(DTd * DTd);
    const float se = (float)(E1 + E2 + E3);

    // per-lane h,g: (batch b0+m, R rows k0..k0+3)
    const int k0 = 16 * w + 4 * q;
    const size_t ho = (size_t)(b0 + m) * RR + k0;
    f32x4 h = *reinterpret_cast<const f32x4*>(Hf + ho);
    const f32x4 g = *reinterpret_cast<const f32x4*>(Gf + ho);

    const int p0 = k0 >> 5;
    const int lp = ((k0 & 31) >> 3) * 16 + m;
    const int j0 = k0 & 7;
    const int hoff = p0 * 1024 + lp * 16 + j0 * 2;

    f32x4 P, Q;
    {   // s = 0
        float h2[4];
        #pragma unroll
        for (int i = 0; i < 4; ++i) h2[i] = h[i] * h[i];
        #pragma unroll
        for (int i = 0; i < 4; ++i) {
            P[i] = (float)D1 * h2[i];
            Q[i] = (float)E1 * h2[i];
        }
        *reinterpret_cast<uint*>(H2B0 + hoff)     = f2bf2(h2[0], h2[1]);
        *reinterpret_cast<uint*>(H2B0 + hoff + 4) = f2bf2(h2[2], h2[3]);
    }

    // M frags -> 32 VGPRs (issued pre-barrier; L2-broadcast)
    const uchar* const mp = ws + M_OFF + ((size_t)(w * 8) << 10) + l * 16;
    uint4v mb[8];
    #pragma unroll
    for (int p = 0; p < 8; ++p)
        mb[p] = *reinterpret_cast<const uint4v*>(mp + ((size_t)p << 10));

    __syncthreads();   // B1: H2B0 ready
    {
        f32x4 acc = {0.f, 0.f, 0.f, 0.f};
        #pragma unroll
        for (int p = 0; p < 8; ++p) {
            const short8 hb = __builtin_bit_cast(short8,
                *reinterpret_cast<const uint4v*>(H2B0 + ((size_t)p << 10) + l * 16));
            acc = __builtin_amdgcn_mfma_f32_16x16x32_bf16(
                      __builtin_bit_cast(short8, mb[p]), hb, acc, 0, 0, 0);
        }
        const float cg = (float)(DTd * D1);
        #pragma unroll
        for (int i = 0; i < 4; ++i) h[i] += cg * (g[i] - acc[i]);
    }
    {   // s = 1 -> H2B1 (double buffer)
        float h2[4];
        #pragma unroll
        for (int i = 0; i < 4; ++i) h2[i] = h[i] * h[i];
        #pragma unroll
        for (int i = 0; i < 4; ++i) {
            P[i] += (float)D2 * h2[i];
            Q[i] += (float)E2 * h2[i];
        }
        *reinterpret_cast<uint*>(H2B1 + hoff)     = f2bf2(h2[0], h2[1]);
        *reinterpret_cast<uint*>(H2B1 + hoff + 4) = f2bf2(h2[2], h2[3]);
    }
    __syncthreads();   // B2: H2B1 ready
    {
        f32x4 acc = {0.f, 0.f, 0.f, 0.f};
        #pragma unroll
        for (int p = 0; p < 8; ++p) {
            const short8 hb = __builtin_bit_cast(short8,
                *reinterpret_cast<const uint4v*>(H2B1 + ((size_t)p << 10) + l * 16));
            acc = __builtin_amdgcn_mfma_f32_16x16x32_bf16(
                      __builtin_bit_cast(short8, mb[p]), hb, acc, 0, 0, 0);
        }
        const float cg = (float)(DTd * D2);
        #pragma unroll
        for (int i = 0; i < 4; ++i) h[i] += cg * (g[i] - acc[i]);
    }
    {   // s = 2: accumulate only
        float h2[4];
        #pragma unroll
        for (int i = 0; i < 4; ++i) h2[i] = h[i] * h[i];
        #pragma unroll
        for (int i = 0; i < 4; ++i) {
            P[i] += (float)D3 * h2[i];
            Q[i] += (float)E3 * h2[i];
        }
    }
    *reinterpret_cast<uint*>(PB + hoff)     = f2bf2(P[0], P[1]);
    *reinterpret_cast<uint*>(PB + hoff + 4) = f2bf2(P[2], P[3]);
    *reinterpret_cast<uint*>(QB + hoff)     = f2bf2(Q[0], Q[1]);
    *reinterpret_cast<uint*>(QB + hoff + 4) = f2bf2(Q[2], Q[3]);

    // phase-3 W prefetch: this half's tiles t0 = dh*32 + 2w, t0+1; 4-deep
    const int t0 = dh * 32 + 2 * w;
    const uchar* const wpb = ws + W_OFF + l * 16;
    uint4v wb[4][2];
    #pragma unroll
    for (int p = 0; p < 4; ++p) {
        wb[p][0] = *reinterpret_cast<const uint4v*>(wpb + (size_t)((t0)     * 8 + p) * 1024);
        wb[p][1] = *reinterpret_cast<const uint4v*>(wpb + (size_t)((t0 + 1) * 8 + p) * 1024);
    }

    __syncthreads();   // B3: PB/QB ready

    f32x4 aV[2] = {{0.f,0.f,0.f,0.f}, {0.f,0.f,0.f,0.f}};
    f32x4 aX[2] = {{0.f,0.f,0.f,0.f}, {0.f,0.f,0.f,0.f}};
    #pragma unroll
    for (int p = 0; p < 8; ++p) {
        const uint4v c0 = wb[p & 3][0];
        const uint4v c1 = wb[p & 3][1];
        if (p < 4) {
            wb[p & 3][0] = *reinterpret_cast<const uint4v*>(
                wpb + (size_t)((t0)     * 8 + p + 4) * 1024);
            wb[p & 3][1] = *reinterpret_cast<const uint4v*>(
                wpb + (size_t)((t0 + 1) * 8 + p + 4) * 1024);
        }
        const short8 pb = __builtin_bit_cast(short8,
            *reinterpret_cast<const uint4v*>(PB + ((size_t)p << 10) + l * 16));
        const short8 qb = __builtin_bit_cast(short8,
            *reinterpret_cast<const uint4v*>(QB + ((size_t)p << 10) + l * 16));
        const short8 w0 = __builtin_bit_cast(short8, c0);
        const short8 w1 = __builtin_bit_cast(short8, c1);
        aV[0] = __builtin_amdgcn_mfma_f32_16x16x32_bf16(w0, pb, aV[0], 0, 0, 0);
        aV[1] = __builtin_amdgcn_mfma_f32_16x16x32_bf16(w1, pb, aV[1], 0, 0, 0);
        aX[0] = __builtin_amdgcn_mfma_f32_16x16x32_bf16(w0, qb, aX[0], 0, 0, 0);
        aX[1] = __builtin_amdgcn_mfma_f32_16x16x32_bf16(w1, qb, aX[1], 0, 0, 0);
    }
    // epilogue: lane holds (batch b0+m, D = (t0+t)*16 + 4q + i), f32 exact
    #pragma unroll
    for (int t = 0; t < 2; ++t) {
        const size_t gib = (size_t)(b0 + m) * DD + (t0 + t) * 16 + 4 * q;
        const float4 fv = *reinterpret_cast<const float4*>(force + gib);
        const float4 v0 = *reinterpret_cast<const float4*>(v_in + gib);
        const float4 x0 = *reinterpret_cast<const float4*>(x_in + gib);
        float4 vo, xo;
        vo.x = v0.x + dtf * fv.x - dtf * aV[t][0];
        vo.y = v0.y + dtf * fv.y - dtf * aV[t][1];
        vo.z = v0.z + dtf * fv.z - dtf * aV[t][2];
        vo.w = v0.w + dtf * fv.w - dtf * aV[t][3];
        xo.x = x0.x + dtf * v0.x + dt2 * se * fv.x - dt2 * aX[t][0];
        xo.y = x0.y + dtf * v0.y + dt2 * se * fv.y - dt2 * aX[t][1];
        xo.z = x0.z + dtf * v0.z + dt2 * se * fv.z - dt2 * aX[t][2];
        xo.w = x0.w + dtf * v0.w + dt2 * se * fv.w - dt2 * aX[t][3];
        *reinterpret_cast<float4*>(v_out + gib) = vo;
        *reinterpret_cast<float4*>(x_out + gib) = xo;
    }
}

extern "C" void kernel_launch(void* const* d_in, const int* in_sizes, int n_in,
                              void* d_out, int out_size, void* d_ws, size_t ws_size,
                              hipStream_t stream) {
    const float* x     = (const float*)d_in[0];
    const float* v     = (const float*)d_in[1];
    const float* force = (const float*)d_in[2];
    const float* U     = (const float*)d_in[3];
    const float* W     = (const float*)d_in[4];

    float* x_out = (float*)d_out;
    float* v_out = x_out + (size_t)BSZ * DD;

    uchar* ws = (uchar*)d_ws;
    float* Hf = (float*)(ws + H_OFF);
    float* Gf = (float*)(ws + G_OFF);

    pack_kernel<<<dim3(192), dim3(256), 0, stream>>>(U, W, ws);
    mm_kernel<<<dim3(64), dim3(256), 0, stream>>>(W, ws);
    hg_kernel<<<dim3(BSZ / 16), dim3(512), 0, stream>>>(v, force, ws, Hf, Gf);
    iter_kernel<<<dim3(2 * BSZ / 16), dim3(1024), 0, stream>>>(
        x, v, force, ws, Hf, Gf, x_out, v_out);
}